// Round 10
// baseline (24.876 us; speedup 1.0000x reference)
//
#include <hip/hip_runtime.h>

#define NCOL 90                 // 5*B + C = 10 + 80
#define LAMBDA_COORD 5.0f
#define LAMBDA_NOOBJ 0.5f

// 4 lanes per cell probe + wave compaction (full-occupancy variant of R9):
//  - lane r of each 4-lane group loads ONE dword: r0=targ[4], r1=targ[9],
//    r2=pred[4], r3=pred[9]; three shfl_xor ops reassemble all four on r0.
//  - noobj term + obj flag on r0 (16 cells/wave); obj cells ballot-compacted
//    into a per-wave queue; wave-uniform rounds of 8 cells x 8 lanes
//    (class sweep cols 10+2r+16k = exact cover of 10..89; box math on r==0).
//  - 12544 waves (49/CU -> full 32/CU occupancy) vs R9's 24.5/CU.
__global__ __launch_bounds__(256, 8) void yolo_cell_kernel(
    const float* __restrict__ pred,
    const float* __restrict__ targ,
    float* __restrict__ partials)
{
    __shared__ int q[4][16];               // per-wave obj queue (n <= 16)
    __shared__ float red[4];

    const float inv_s = 1.0f / 7.0f;
    const int lane = threadIdx.x & 63;
    const int wave = threadIdx.x >> 6;
    const int tid  = blockIdx.x * 256 + threadIdx.x;
    const int cell = tid >> 2;             // 4 lanes per cell (grid exact)
    const int r4   = tid & 3;

    const float* pc = pred + (size_t)cell * NCOL;
    const float* tc = targ + (size_t)cell * NCOL;

    // ---- one probe load per lane ----
    const float* src = (r4 < 2) ? tc : pc;
    float v  = src[(r4 & 1) ? 9 : 4];
    float x1 = __shfl_xor(v, 1, 64);       // r0: targ[9]
    float x2 = __shfl_xor(v, 2, 64);       // r0: pred[4]
    float x3 = __shfl_xor(x1, 2, 64);      // r0: pred[9]

    float loss = 0.0f;
    bool obj = false;
    if (r4 == 0) {                         // r0 owns the cell's probe math
        float t4 = v;
        if (t4 == 0.0f) {                  // noobj confidence term
            float d4 = x2 - v;             // pred[4] - targ[4]
            float d9 = x3 - x1;            // pred[9] - targ[9]
            loss = LAMBDA_NOOBJ * (d4 * d4 + d9 * d9);
        }
        obj = (t4 > 0.0f);
    }

    // ---- compact obj cells into per-wave queue ----
    unsigned long long m = __ballot(obj);
    int n = __popcll(m);
    if (obj) {
        int pos = __popcll(m & ((1ull << lane) - 1ull));
        q[wave][pos] = cell;
    }
    __builtin_amdgcn_sched_barrier(0);     // pin write->read order in program

    // ---- obj rounds: 8 cells x 8 lanes, wave-uniform; n <= 16 -> <= 2 rounds
    const int g = lane >> 3;               // cell slot 0..7
    const int r = lane & 7;                // lane within cell group

    auto do_round = [&](int j) {
        int qi = j * 8 + g;
        bool valid = (qi < n);
        int oc = q[wave][valid ? qi : 0];
        const float* opc = pred + (size_t)oc * NCOL;
        const float* otc = targ + (size_t)oc * NCOL;

        if (valid) {
            // class term: lane r covers float2s at cols 10+2r+16k
            float2 pcv[5], tcv[5];
#pragma unroll
            for (int k = 0; k < 5; ++k)
                pcv[k] = *reinterpret_cast<const float2*>(opc + 10 + 2 * r + 16 * k);
#pragma unroll
            for (int k = 0; k < 5; ++k)
                tcv[k] = *reinterpret_cast<const float2*>(otc + 10 + 2 * r + 16 * k);

            float cls = 0.0f;
#pragma unroll
            for (int k = 0; k < 5; ++k) {
                float dx = pcv[k].x - tcv[k].x;
                float dy = pcv[k].y - tcv[k].y;
                cls += dx * dx + dy * dy;
            }
            loss += cls;

            if (r == 0) {                  // box + conf math, 1 lane per cell
                float p[10], t[10];
#pragma unroll
                for (int i = 0; i < 5; ++i) {
                    float2 av = *reinterpret_cast<const float2*>(opc + 2 * i);
                    float2 bv = *reinterpret_cast<const float2*>(otc + 2 * i);
                    p[2*i] = av.x; p[2*i+1] = av.y;
                    t[2*i] = bv.x; t[2*i+1] = bv.y;
                }

                float tax = t[0] * inv_s - 0.5f * t[2];
                float tay = t[1] * inv_s - 0.5f * t[3];
                float tbx = tax * inv_s + 0.5f * t[2];
                float tby = tay * inv_s + 0.5f * t[3];
                float t_area = (tbx - tax) * (tby - tay);

                float pax[2], pay[2], pbx[2], pby[2], iou[2];
#pragma unroll
                for (int bb = 0; bb < 2; ++bb) {
                    const float* qq = p + 5 * bb;
                    float ax = qq[0] * inv_s - 0.5f * qq[2];
                    float ay = qq[1] * inv_s - 0.5f * qq[3];
                    float bx = ax * inv_s + 0.5f * qq[2];
                    float by = ay * inv_s + 0.5f * qq[3];
                    pax[bb] = ax; pay[bb] = ay; pbx[bb] = bx; pby[bb] = by;
                    float tlx = fmaxf(ax, tax);
                    float tly = fmaxf(ay, tay);
                    float brx = fminf(bx, tbx);
                    float bry = fminf(by, tby);
                    float w = fmaxf(brx - tlx, 0.0f);
                    float h = fmaxf(bry - tly, 0.0f);
                    float inter = w * h;
                    float parea = (bx - ax) * (by - ay);
                    iou[bb] = inter / (parea + t_area - inter);
                }

                int idx = (iou[1] > iou[0]) ? 1 : 0;   // first-max-on-tie
                float tiou = idx ? iou[1] : iou[0];

                float psx = idx ? pax[1] : pax[0];
                float psy = idx ? pay[1] : pay[0];
                float psw = idx ? pbx[1] : pbx[0];
                float psh = idx ? pby[1] : pby[0];
                float psc = idx ? p[9] : p[4];

                float tsx, tsy, tsw, tsh;   // transformed 1st box or RAW 2nd
                if (idx == 0) { tsx = tax; tsy = tay; tsw = tbx; tsh = tby; }
                else          { tsx = t[5]; tsy = t[6]; tsw = t[7]; tsh = t[8]; }

                float dx = psx - tsx;
                float dy = psy - tsy;
                float dw = psw - tsw;
                float dh = psh - tsh;
                float xy = dx * dx + dy * dy;
                float wh = dw * dw + dh * dh;
                float dc = psc - tiou;

                loss += LAMBDA_COORD * (xy + wh) + dc * dc;
            }
        }
    };

    if (n > 0) do_round(0);
    if (n > 8) do_round(1);                // n <= 16 always: no tail loop

    // ---- wave + block reduce, plain partial store ----
#pragma unroll
    for (int off = 32; off > 0; off >>= 1)
        loss += __shfl_down(loss, off, 64);
    if (lane == 0) red[wave] = loss;
    __syncthreads();
    if (threadIdx.x == 0)
        partials[blockIdx.x] = red[0] + red[1] + red[2] + red[3];
}

// Single-wave finisher: 3136 partials = 784 float4, no LDS, no barrier.
__global__ __launch_bounds__(64) void yolo_reduce_kernel(
    const float* __restrict__ partials, float* __restrict__ out)
{
    const float4* p4 = reinterpret_cast<const float4*>(partials);
    float s = 0.0f;
    for (int i = threadIdx.x; i < 784; i += 64) {
        float4 v = p4[i];
        s += (v.x + v.y) + (v.z + v.w);
    }
#pragma unroll
    for (int off = 32; off > 0; off >>= 1)
        s += __shfl_down(s, off, 64);
    if (threadIdx.x == 0)
        out[0] = s * (1.0f / 4096.0f);
}

extern "C" void kernel_launch(void* const* d_in, const int* in_sizes, int n_in,
                              void* d_out, int out_size, void* d_ws, size_t ws_size,
                              hipStream_t stream) {
    const float* pred = (const float*)d_in[0];
    const float* targ = (const float*)d_in[1];
    float* out = (float*)d_out;

    int ncells  = in_sizes[0] / NCOL;        // 200704
    int nblocks = ncells * 4 / 256;          // 3136 (exact)

    float* partials = (float*)d_ws;          // 3136 floats scratch

    yolo_cell_kernel<<<nblocks, 256, 0, stream>>>(pred, targ, partials);
    yolo_reduce_kernel<<<1, 64, 0, stream>>>(partials, out);
}

// Round 11
// 22.545 us; speedup vs baseline: 1.1034x; 1.1034x over previous
//
#include <hip/hip_runtime.h>

#define NCOL 90                 // 5*B + C = 10 + 80
#define LAMBDA_COORD 5.0f
#define LAMBDA_NOOBJ 0.5f

// R9 structure (best: 23.8 us) — 2 lanes per cell probe + wave compaction:
//  - pair-split probe: even lane loads targ[4],targ[9], odd lane pred[4],pred[9]
//    of the SAME cell; one shfl_xor(1) exchange -> noobj term on even lanes.
//  - obj cells (~25% of the wave's 32 cells) ballot-compacted into a per-wave
//    queue; processed in wave-uniform rounds of 8 cells x 8 lanes
//    (class sweep cols 10+2r+16k = exact cover of 10..89; box math on r==0).
//  - 6272 waves (24.5/CU): R10 proved more waves doesn't help (scattered-line
//    HBM floor is binding, ~83 MB irreducible line traffic).
__global__ __launch_bounds__(256, 6) void yolo_cell_kernel(
    const float* __restrict__ pred,
    const float* __restrict__ targ,
    float* __restrict__ partials)
{
    __shared__ int q[4][32];               // per-wave obj queue
    __shared__ float red[4];

    const float inv_s = 1.0f / 7.0f;
    const int lane = threadIdx.x & 63;
    const int wave = threadIdx.x >> 6;
    const int tid  = blockIdx.x * 256 + threadIdx.x;
    const int cell = tid >> 1;             // 2 lanes per cell (grid exact)
    const bool is_even = (lane & 1) == 0;

    const float* pc = pred + (size_t)cell * NCOL;
    const float* tc = targ + (size_t)cell * NCOL;

    // ---- pair-split probe, one round-trip ----
    const float* src = is_even ? tc : pc;
    float a = src[4];
    float b = src[9];
    float oa = __shfl_xor(a, 1, 64);       // even gets pred[4], odd gets targ[4]
    float ob = __shfl_xor(b, 1, 64);       // even gets pred[9], odd gets targ[9]

    float loss = 0.0f;
    bool obj = false;
    if (is_even) {                         // even lane owns the cell's probe math
        float t4 = a;
        if (t4 == 0.0f) {                  // noobj confidence term
            float d4 = oa - a;             // pred[4] - targ[4]
            float d9 = ob - b;             // pred[9] - targ[9]
            loss = LAMBDA_NOOBJ * (d4 * d4 + d9 * d9);
        }
        obj = (t4 > 0.0f);
    }

    // ---- compact obj cells into per-wave queue ----
    unsigned long long m = __ballot(obj);
    int n = __popcll(m);
    if (obj) {
        int pos = __popcll(m & ((1ull << lane) - 1ull));
        q[wave][pos] = cell;
    }
    __builtin_amdgcn_sched_barrier(0);     // pin write->read order in program

    // ---- obj rounds: 8 cells x 8 lanes, wave-uniform trip count ----
    const int g = lane >> 3;               // cell slot 0..7
    const int r = lane & 7;                // lane within cell group

    auto do_round = [&](int j) {
        int qi = j * 8 + g;
        bool valid = (qi < n);
        int oc = q[wave][valid ? qi : 0];
        const float* opc = pred + (size_t)oc * NCOL;
        const float* otc = targ + (size_t)oc * NCOL;

        if (valid) {
            // class term: lane r covers float2s at cols 10+2r+16k
            float2 pcv[5], tcv[5];
#pragma unroll
            for (int k = 0; k < 5; ++k)
                pcv[k] = *reinterpret_cast<const float2*>(opc + 10 + 2 * r + 16 * k);
#pragma unroll
            for (int k = 0; k < 5; ++k)
                tcv[k] = *reinterpret_cast<const float2*>(otc + 10 + 2 * r + 16 * k);

            float cls = 0.0f;
#pragma unroll
            for (int k = 0; k < 5; ++k) {
                float dx = pcv[k].x - tcv[k].x;
                float dy = pcv[k].y - tcv[k].y;
                cls += dx * dx + dy * dy;
            }
            loss += cls;

            if (r == 0) {                  // box + conf math, 1 lane per cell
                float p[10], t[10];
#pragma unroll
                for (int i = 0; i < 5; ++i) {
                    float2 av = *reinterpret_cast<const float2*>(opc + 2 * i);
                    float2 bv = *reinterpret_cast<const float2*>(otc + 2 * i);
                    p[2*i] = av.x; p[2*i+1] = av.y;
                    t[2*i] = bv.x; t[2*i+1] = bv.y;
                }

                float tax = t[0] * inv_s - 0.5f * t[2];
                float tay = t[1] * inv_s - 0.5f * t[3];
                float tbx = tax * inv_s + 0.5f * t[2];
                float tby = tay * inv_s + 0.5f * t[3];
                float t_area = (tbx - tax) * (tby - tay);

                float pax[2], pay[2], pbx[2], pby[2], iou[2];
#pragma unroll
                for (int bb = 0; bb < 2; ++bb) {
                    const float* qq = p + 5 * bb;
                    float ax = qq[0] * inv_s - 0.5f * qq[2];
                    float ay = qq[1] * inv_s - 0.5f * qq[3];
                    float bx = ax * inv_s + 0.5f * qq[2];
                    float by = ay * inv_s + 0.5f * qq[3];
                    pax[bb] = ax; pay[bb] = ay; pbx[bb] = bx; pby[bb] = by;
                    float tlx = fmaxf(ax, tax);
                    float tly = fmaxf(ay, tay);
                    float brx = fminf(bx, tbx);
                    float bry = fminf(by, tby);
                    float w = fmaxf(brx - tlx, 0.0f);
                    float h = fmaxf(bry - tly, 0.0f);
                    float inter = w * h;
                    float parea = (bx - ax) * (by - ay);
                    iou[bb] = inter / (parea + t_area - inter);
                }

                int idx = (iou[1] > iou[0]) ? 1 : 0;   // first-max-on-tie
                float tiou = idx ? iou[1] : iou[0];

                float psx = idx ? pax[1] : pax[0];
                float psy = idx ? pay[1] : pay[0];
                float psw = idx ? pbx[1] : pbx[0];
                float psh = idx ? pby[1] : pby[0];
                float psc = idx ? p[9] : p[4];

                float tsx, tsy, tsw, tsh;   // transformed 1st box or RAW 2nd
                if (idx == 0) { tsx = tax; tsy = tay; tsw = tbx; tsh = tby; }
                else          { tsx = t[5]; tsy = t[6]; tsw = t[7]; tsh = t[8]; }

                float dx = psx - tsx;
                float dy = psy - tsy;
                float dw = psw - tsw;
                float dh = psh - tsh;
                float xy = dx * dx + dy * dy;
                float wh = dw * dw + dh * dh;
                float dc = psc - tiou;

                loss += LAMBDA_COORD * (xy + wh) + dc * dc;
            }
        }
    };

    if (n > 0) do_round(0);
    if (n > 8) do_round(1);
    for (int j = 2; j * 8 < n; ++j) do_round(j);   // rare tail (n>16)

    // ---- wave + block reduce, plain partial store ----
#pragma unroll
    for (int off = 32; off > 0; off >>= 1)
        loss += __shfl_down(loss, off, 64);
    if (lane == 0) red[wave] = loss;
    __syncthreads();
    if (threadIdx.x == 0)
        partials[blockIdx.x] = red[0] + red[1] + red[2] + red[3];
}

// Finisher: 1568 partials = 392 float4, one 256-thread block.
__global__ __launch_bounds__(256) void yolo_reduce_kernel(
    const float* __restrict__ partials, float* __restrict__ out)
{
    const float4* p4 = reinterpret_cast<const float4*>(partials);
    float s = 0.0f;
    for (int i = threadIdx.x; i < 392; i += 256) {
        float4 v = p4[i];
        s += (v.x + v.y) + (v.z + v.w);
    }
#pragma unroll
    for (int off = 32; off > 0; off >>= 1)
        s += __shfl_down(s, off, 64);

    __shared__ float red[4];
    int lane = threadIdx.x & 63;
    int wid  = threadIdx.x >> 6;
    if (lane == 0) red[wid] = s;
    __syncthreads();
    if (threadIdx.x == 0)
        out[0] = (red[0] + red[1] + red[2] + red[3]) * (1.0f / 4096.0f);
}

extern "C" void kernel_launch(void* const* d_in, const int* in_sizes, int n_in,
                              void* d_out, int out_size, void* d_ws, size_t ws_size,
                              hipStream_t stream) {
    const float* pred = (const float*)d_in[0];
    const float* targ = (const float*)d_in[1];
    float* out = (float*)d_out;

    int ncells  = in_sizes[0] / NCOL;        // 200704
    int nblocks = ncells * 2 / 256;          // 1568 (exact)

    float* partials = (float*)d_ws;          // 1568 floats scratch

    yolo_cell_kernel<<<nblocks, 256, 0, stream>>>(pred, targ, partials);
    yolo_reduce_kernel<<<1, 256, 0, stream>>>(partials, out);
}